// Round 8
// baseline (13260.080 us; speedup 1.0000x reference)
//
#include <hip/hip_runtime.h>
#include <hip/hip_cooperative_groups.h>

namespace cg = cooperative_groups;

// Problem constants (shapes fixed by the reference)
#define HP    1017
#define WP    1017
#define NPIX  (HP*WP)          // 1034289
#define N3    (NPIX/3)         // 344763
#define NSEG  4041             // ceil(NPIX/256)
#define W_IMG 1024
#define RATE  0.001f
#define EPSV  1e-7f
#define NBLOCKS 1024           // 4 blocks/CU on 256 CUs — residency FORCED by launch_bounds

typedef _Float16 half_t;

__device__ __forceinline__ float fast_rcp(float x) { return __builtin_amdgcn_rcpf(x); }

// ---------------------------------------------------------------------------
// sig core: given reciprocals r0/rm/rp of (guarded) t at m, m-1, m+1
// ---------------------------------------------------------------------------
__device__ __forceinline__ float sig_at(int m, float r0, float rm, float rp,
                                        const half_t* __restrict__ img_c,
                                        float A0, float A1, float A2) {
    int base = 3 * m;
    float fm1 = (float)img_c[m > 0        ? base - 1 : 0];
    float f0  = (float)img_c[base + 0];
    float f1  = (float)img_c[base + 1];
    float f2  = (float)img_c[base + 2];
    float f3  = (float)img_c[m < NPIX - 1 ? base + 3 : base + 2];
    float dm1 = (fm1 - A2) * rm + A2;
    float d0  = (f0  - A0) * r0 + A0;
    float d1  = (f1  - A1) * r0 + A1;
    float d2  = (f2  - A2) * r0 + A2;
    float d3  = (f3  - A0) * rp + A0;
    float y0 = 0.5f * (d1 - dm1);
    float y1 = 0.5f * (d2 - d0);
    float y2 = 0.5f * (d3 - d1);
    if (m == 0      ) y0 = d1 - d0;
    if (m == N3     ) y0 = d1 - d0;
    if (m == 2*N3   ) y0 = d1 - d0;
    if (m == N3 - 1 ) y2 = d2 - d1;
    if (m == 2*N3-1 ) y2 = d2 - d1;
    if (m == NPIX-1 ) y2 = d2 - d1;
    float l2 = sqrtf(y0*y0 + y1*y1 + y2*y2);
    return fast_rcp(1.0f + __expf(48.0f * (l2 - 0.1f)));
}

// ---------------------------------------------------------------------------
// GD-update stencil at flat index m (stored lg => short load->FMA chains)
// ---------------------------------------------------------------------------
__device__ __forceinline__ float tnew_at(int m, const float* __restrict__ t,
                                         const float* __restrict__ lg,
                                         const half_t* __restrict__ sig) {
    int a = m / WP;
    int b = m - a * WP;
    float tc = t[m];
    float w0 = (tc <= 0.0f) ? EPSV : tc;
    float lgC = lg[m];
    float acc = 0.0f;
    if (b >= 1) {
        float lgW = (b >= 2) ? lg[m-2] : 0.0f;
        acc += (lgC - lgW) * (float)sig[m-1];
    }
    if (b <= WP-2) {
        float lgE = (b <= WP-3) ? lg[m+2] : 0.0f;
        acc -= (lgE - lgC) * (float)sig[m+1];
    }
    if (a <= HP-2) {
        float lgS = (a <= HP-3) ? lg[m+2*WP] : 0.0f;
        acc += (lgC - lgS) * (float)sig[m+WP];
    }
    if (a >= 1) {
        float lgN = (a >= 2) ? lg[m-2*WP] : 0.0f;
        acc -= (lgN - lgC) * (float)sig[m-WP];
    }
    return w0 - RATE * 2.0f * acc * fast_rcp(w0);
}

// ---------------------------------------------------------------------------
// persistent cooperative kernel: init + sig0 + 99 fused iters + final output
// __launch_bounds__(256, 4): 4 waves/EU => 16 waves/CU => 4 blocks/CU of 256
// threads guaranteed schedulable (VGPR capped at 128) => 1024 blocks co-resident.
// ---------------------------------------------------------------------------
__global__ __launch_bounds__(256, 4) void persist_kernel(
    const float* __restrict__ img, const float* __restrict__ A,
    float* __restrict__ t_a, float* __restrict__ t_b,
    float* __restrict__ lg_a, float* __restrict__ lg_b,
    half_t* __restrict__ img_c, half_t* __restrict__ sig_a, half_t* __restrict__ sig_b,
    float* __restrict__ out)
{
    cg::grid_group grid = cg::this_grid();
    const int tid      = threadIdx.x;
    const int nthreads = gridDim.x * 256;
    const int gtid     = blockIdx.x * 256 + tid;
    __shared__ float rl[258];

    const float A0 = A[0], A1 = A[1], A2 = A[2];

    // ---- phase 0: init (img_c fp16 pack + t0 = tlb) ----
    for (int m = gtid; m < NPIX; m += nthreads) {
        int a = m / WP, b = m - a * WP;
        const float* src = img + ((size_t)a * W_IMG + b) * 3;
        img_c[3*m+0] = (half_t)src[0];
        img_c[3*m+1] = (half_t)src[1];
        img_c[3*m+2] = (half_t)src[2];
        const float* cen = img + ((size_t)(a+3) * W_IMG + (b+3)) * 3;
        float t = 1.0f - cen[0] / A0;
        t = fmaxf(t, 1.0f - cen[1] / A1);
        t = fmaxf(t, 1.0f - cen[2] / A2);
        t_a[m] = t;
    }
    grid.sync();

    // ---- phase 1: sig0 + lg0 from t0 ----
    for (int m = gtid; m < NPIX; m += nthreads) {
        float t0 = t_a[m];
        float r0 = fast_rcp(t0);
        float rm = fast_rcp(t_a[m > 0 ? m - 1 : 0]);
        float rp = fast_rcp(t_a[m < NPIX-1 ? m + 1 : NPIX-1]);
        sig_a[m] = (half_t)sig_at(m, r0, rm, rp, img_c, A0, A1, A2);
        lg_a[m]  = __logf(t0 <= 0.0f ? EPSV : t0);
    }
    grid.sync();

    // ---- 99 fused iterations ----
    for (int it = 0; it < 99; ++it) {
        const float*  t  = (it & 1) ? t_b  : t_a;
        const float*  lg = (it & 1) ? lg_b : lg_a;
        const half_t* sg = (it & 1) ? sig_b : sig_a;
        float*  tno = (it & 1) ? t_a  : t_b;
        float*  lgo = (it & 1) ? lg_a : lg_b;
        half_t* sgo = (it & 1) ? sig_a : sig_b;

        for (int seg = blockIdx.x; seg < NSEG; seg += gridDim.x) {
            const int s = seg * 256;
            const int m = s + tid;
            const bool active = (m < NPIX);
            float tn = 1.0f, r0 = 1.0f;
            if (active) {
                tn = tnew_at(m, t, lg, sg);
                r0 = fast_rcp(tn);
                rl[tid + 1] = r0;
                tno[m] = tn;
                lgo[m] = __logf(tn <= 0.0f ? EPSV : tn);
            }
            if (tid == 0) {            // left halo (wave 0)
                rl[0] = fast_rcp(tnew_at(s > 0 ? s - 1 : 0, t, lg, sg));
            } else if (tid == 64) {    // right halo (wave 1, parallel with wave 0)
                int mr = s + 256; if (mr > NPIX - 1) mr = NPIX - 1;
                rl[257] = fast_rcp(tnew_at(mr, t, lg, sg));
            }
            __syncthreads();
            if (active) {
                float rm = (m > 0)        ? rl[tid]     : r0;
                float rp = (m < NPIX - 1) ? rl[tid + 2] : r0;
                sgo[m] = (half_t)sig_at(m, r0, rm, rp, img_c, A0, A1, A2);
            }
            __syncthreads();           // protect rl before next segment reuses it
        }
        grid.sync();
    }

    // ---- final: iteration 100 fused with dehaze output (src parity: b) ----
    for (int m = gtid; m < NPIX; m += nthreads) {
        float tn = tnew_at(m, t_b, lg_b, sig_b);
        float r = 1.0f / tn;           // precise div for the final output
        out[3*m+0] = ((float)img_c[3*m+0] - A0) * r + A0;
        out[3*m+1] = ((float)img_c[3*m+1] - A1) * r + A1;
        out[3*m+2] = ((float)img_c[3*m+2] - A2) * r + A2;
    }
}

extern "C" void kernel_launch(void* const* d_in, const int* in_sizes, int n_in,
                              void* d_out, int out_size, void* d_ws, size_t ws_size,
                              hipStream_t stream) {
    const float* img = (const float*)d_in[0];
    const float* A   = (const float*)d_in[1];
    // workspace: t_a,t_b,lg_a,lg_b [N] f32 | img_c[3N] f16 | sig_a,sig_b [N] f16
    float*  ws    = (float*)d_ws;
    float*  t_a   = ws;
    float*  t_b   = t_a + NPIX;
    float*  lg_a  = t_b + NPIX;
    float*  lg_b  = lg_a + NPIX;
    half_t* img_c = (half_t*)(lg_b + NPIX);
    half_t* sig_a = img_c + ((size_t)3 * NPIX + 1);   // +1 pads keep 4B alignment
    half_t* sig_b = sig_a + (NPIX + 1);
    float*  outp  = (float*)d_out;

    void* args[] = {
        (void*)&img, (void*)&A,
        (void*)&t_a, (void*)&t_b, (void*)&lg_a, (void*)&lg_b,
        (void*)&img_c, (void*)&sig_a, (void*)&sig_b, (void*)&outp
    };
    hipLaunchCooperativeKernel((const void*)persist_kernel,
                               dim3(NBLOCKS), dim3(256), args, 0, stream);
}

// Round 9
// 1406.538 us; speedup vs baseline: 9.4275x; 9.4275x over previous
//
#include <hip/hip_runtime.h>

// Problem constants (shapes fixed by the reference)
#define HP    1017
#define WP    1017
#define NPIX  (HP*WP)          // 1034289
#define N3    (NPIX/3)         // 344763
#define W_IMG 1024
#define RATE  0.001f
#define EPSV  1e-7f

// temporal blocking geometry
#define K_ITERS 4
#define RY   16                // output rows per band
#define CW   255               // output cols per col-tile
#define HALO 8                 // 2*K_ITERS
#define IY   (RY + 2*HALO)     // 32
#define IC   (CW + 2*HALO)     // 271
#define ICP  272               // padded LDS stride
#define NBX  4                 // col tiles (4*255 = 1020 >= 1017)
#define NBY  64                // row bands (64*16 = 1024 >= 1017)
#define TBT  1024              // threads per tb block

typedef _Float16 half_t;

__device__ __forceinline__ float fast_rcp(float x) { return __builtin_amdgcn_rcpf(x); }
__device__ __forceinline__ float LGf(float tv) { return __logf(tv <= 0.0f ? EPSV : tv); }

// ---------------------------------------------------------------------------
// init: t0 = tlb = max_c(1 - center/A), and pack img_c (fp16) contiguously
// ---------------------------------------------------------------------------
__global__ void init_kernel(const float* __restrict__ img, const float* __restrict__ A,
                            half_t* __restrict__ img_c, float* __restrict__ t0) {
    int b = blockIdx.x * blockDim.x + threadIdx.x;
    int a = blockIdx.y;
    if (b >= WP) return;
    int m = a * WP + b;
    float A0 = A[0], A1 = A[1], A2 = A[2];
    const float* src = img + ((size_t)a * W_IMG + b) * 3;
    img_c[3*m+0] = (half_t)src[0];
    img_c[3*m+1] = (half_t)src[1];
    img_c[3*m+2] = (half_t)src[2];
    const float* cen = img + ((size_t)(a+3) * W_IMG + (b+3)) * 3;
    float t = 1.0f - cen[0] / A0;
    t = fmaxf(t, 1.0f - cen[1] / A1);
    t = fmaxf(t, 1.0f - cen[2] / A2);
    t0[m] = t;
}

// ---------------------------------------------------------------------------
// sig core (flat semantics): t0v/tmv/tpv = RAW t at m, m-1, m+1 (caller clamps)
// ---------------------------------------------------------------------------
__device__ __forceinline__ float sig_eval(int m, float t0v, float tmv, float tpv,
                                          const half_t* __restrict__ img_c,
                                          float A0, float A1, float A2) {
    float r0 = fast_rcp(t0v), rm = fast_rcp(tmv), rp = fast_rcp(tpv);
    int base = 3 * m;
    float fm1 = (float)img_c[m > 0        ? base - 1 : 0];
    float f0  = (float)img_c[base + 0];
    float f1  = (float)img_c[base + 1];
    float f2  = (float)img_c[base + 2];
    float f3  = (float)img_c[m < NPIX - 1 ? base + 3 : base + 2];
    float dm1 = (fm1 - A2) * rm + A2;
    float d0  = (f0  - A0) * r0 + A0;
    float d1  = (f1  - A1) * r0 + A1;
    float d2  = (f2  - A2) * r0 + A2;
    float d3  = (f3  - A0) * rp + A0;
    float y0 = 0.5f * (d1 - dm1);
    float y1 = 0.5f * (d2 - d0);
    float y2 = 0.5f * (d3 - d1);
    if (m == 0      ) y0 = d1 - d0;
    if (m == N3     ) y0 = d1 - d0;
    if (m == 2*N3   ) y0 = d1 - d0;
    if (m == N3 - 1 ) y2 = d2 - d1;
    if (m == 2*N3-1 ) y2 = d2 - d1;
    if (m == NPIX-1 ) y2 = d2 - d1;
    float l2 = sqrtf(y0*y0 + y1*y1 + y2*y2);
    return fast_rcp(1.0f + __expf(48.0f * (l2 - 0.1f)));
}

// ---------------------------------------------------------------------------
// temporal-blocked kernel: K_ITERS GD iterations entirely in LDS.
// Tile cell (i,j) hosts flat pixel m = (rbase+i)*WP + (cbase+j); cols may run
// past [0,WP) — flat wrap semantics are then automatic. All boundary behavior
// driven by true (a,b) and flat-m conditionals.
// ---------------------------------------------------------------------------
__global__ __launch_bounds__(TBT) void tb_kernel(
    const float* __restrict__ tin, float* __restrict__ tout,
    const half_t* __restrict__ img_c, const float* __restrict__ A)
{
    __shared__ float tls[2][IY][ICP];
    __shared__ float sgl[IY][ICP];
    const int tid   = threadIdx.x;
    const int rbase = blockIdx.y * RY - HALO;
    const int cbase = blockIdx.x * CW - HALO;
    const float A0 = A[0], A1 = A[1], A2 = A[2];

    // load t_k (raw) into tls[0]
    for (int cell = tid; cell < IY * IC; cell += TBT) {
        int i = cell / IC, j = cell - i * IC;
        int m = (rbase + i) * WP + (cbase + j);
        float v = 1.0f;
        if (m >= 0 && m < NPIX) v = tin[m];
        tls[0][i][j] = v;
    }
    __syncthreads();

    int cur = 0;
    #pragma unroll 1
    for (int lvl = 0; lvl < K_ITERS; ++lvl) {
        const int ms = 2 * lvl + 1;
        // --- sig level (from raw t level lvl) ---
        for (int cell = tid; cell < IY * IC; cell += TBT) {
            int i = cell / IC, j = cell - i * IC;
            float s = 0.0f;
            if (i >= ms && i < IY - ms && j >= ms && j < IC - ms) {
                int m = (rbase + i) * WP + (cbase + j);
                if (m >= 0 && m < NPIX) {
                    float t0v = tls[cur][i][j];
                    float tmv = (m > 0)        ? tls[cur][i][j-1] : t0v;
                    float tpv = (m < NPIX - 1) ? tls[cur][i][j+1] : t0v;
                    s = sig_eval(m, t0v, tmv, tpv, img_c, A0, A1, A2);
                }
            }
            sgl[i][j] = s;
        }
        __syncthreads();
        // --- t level lvl+1 ---
        const int mt = 2 * lvl + 2;
        const int nxt = cur ^ 1;
        for (int cell = tid; cell < IY * IC; cell += TBT) {
            int i = cell / IC, j = cell - i * IC;
            float v = 1.0f;
            if (i >= mt && i < IY - mt && j >= mt && j < IC - mt) {
                int m = (rbase + i) * WP + (cbase + j);
                if (m >= 0 && m < NPIX) {
                    int a = m / WP;
                    int b = m - a * WP;
                    float tc = tls[cur][i][j];
                    float w0 = (tc <= 0.0f) ? EPSV : tc;
                    float lgC = __logf(w0);
                    float acc = 0.0f;
                    if (b >= 1) {
                        float lgW = (b >= 2) ? LGf(tls[cur][i][j-2]) : 0.0f;
                        acc += (lgC - lgW) * sgl[i][j-1];
                    }
                    if (b <= WP-2) {
                        float lgE = (b <= WP-3) ? LGf(tls[cur][i][j+2]) : 0.0f;
                        acc -= (lgE - lgC) * sgl[i][j+1];
                    }
                    if (a <= HP-2) {
                        float lgS = (a <= HP-3) ? LGf(tls[cur][i+2][j]) : 0.0f;
                        acc += (lgC - lgS) * sgl[i+1][j];
                    }
                    if (a >= 1) {
                        float lgN = (a >= 2) ? LGf(tls[cur][i-2][j]) : 0.0f;
                        acc -= (lgN - lgC) * sgl[i-1][j];
                    }
                    v = w0 - RATE * 2.0f * acc * fast_rcp(w0);
                }
            }
            tls[nxt][i][j] = v;
        }
        __syncthreads();
        cur = nxt;
    }

    // write t_{k+4} for the owned output region
    for (int cell = tid; cell < IY * IC; cell += TBT) {
        int i = cell / IC, j = cell - i * IC;
        if (i >= HALO && i < HALO + RY && j >= HALO && j < HALO + CW) {
            int r = rbase + i;
            int c = cbase + j;
            if (r >= 0 && r < HP && c < WP) {
                tout[r * WP + c] = tls[cur][i][j];
            }
        }
    }
}

// ---------------------------------------------------------------------------
// final dehaze from t_100
// ---------------------------------------------------------------------------
__global__ void out_kernel(const float* __restrict__ t, const half_t* __restrict__ img_c,
                           const float* __restrict__ A, float* __restrict__ out) {
    int m = blockIdx.x * blockDim.x + threadIdx.x;
    if (m >= NPIX) return;
    float tv = t[m];
    float A0 = A[0], A1 = A[1], A2 = A[2];
    float r = 1.0f / tv;               // precise div for the final output
    out[3*m+0] = ((float)img_c[3*m+0] - A0) * r + A0;
    out[3*m+1] = ((float)img_c[3*m+1] - A1) * r + A1;
    out[3*m+2] = ((float)img_c[3*m+2] - A2) * r + A2;
}

extern "C" void kernel_launch(void* const* d_in, const int* in_sizes, int n_in,
                              void* d_out, int out_size, void* d_ws, size_t ws_size,
                              hipStream_t stream) {
    const float* img = (const float*)d_in[0];
    const float* A   = (const float*)d_in[1];
    // workspace: t_a[N] f32 | t_b[N] f32 | img_c[3N] f16
    float*  ws    = (float*)d_ws;
    float*  t_a   = ws;
    float*  t_b   = t_a + NPIX;
    half_t* img_c = (half_t*)(t_b + NPIX);

    dim3 blk2(256, 1, 1);
    dim3 grd2((WP + 255) / 256, HP, 1);
    int blk1 = 256;
    int grd1 = (NPIX + blk1 - 1) / blk1;

    hipLaunchKernelGGL(init_kernel, grd2, blk2, 0, stream, img, A, img_c, t_a);

    float* tsrc = t_a;
    float* tdst = t_b;
    for (int d = 0; d < 25; ++d) {               // 25 dispatches x 4 iters = 100
        hipLaunchKernelGGL(tb_kernel, dim3(NBX, NBY), dim3(TBT), 0, stream,
                           tsrc, tdst, img_c, A);
        float* tmp = tsrc; tsrc = tdst; tdst = tmp;
    }
    hipLaunchKernelGGL(out_kernel, dim3(grd1), dim3(blk1), 0, stream,
                       tsrc, img_c, A, (float*)d_out);
}